// Round 11
// baseline (313.678 us; speedup 1.0000x reference)
//
#include <hip/hip_runtime.h>

#define NEG_SLOPE 0.2f
#define BN_EPS 1e-5f
#define LN_EPS 1e-5f

#if __has_builtin(__builtin_amdgcn_exp2f)
#define EXP2F(x) __builtin_amdgcn_exp2f(x)
#else
#define EXP2F(x) exp2f(x)
#endif

typedef __bf16 bf16_t;
typedef bf16_t bf16x8 __attribute__((ext_vector_type(8)));
typedef float floatx4 __attribute__((ext_vector_type(4)));

__device__ __forceinline__ unsigned short f2bf(float f) {
  unsigned u = __float_as_uint(f);
  u += 0x7FFFu + ((u >> 16) & 1u);
  return (unsigned short)(u >> 16);
}
__device__ __forceinline__ float bf_lo(unsigned u) { return __uint_as_float(u << 16); }
__device__ __forceinline__ float bf_hi(unsigned u) { return __uint_as_float(u & 0xFFFF0000u); }

// ---------------- fused: conversions + BN fold + XCD-privatized degree count ----------------
__global__ void cvt_all(const float* __restrict__ x,
                        const float* __restrict__ wl1, const float* __restrict__ wr1,
                        const float* __restrict__ wl2, const float* __restrict__ wr2,
                        const float* __restrict__ wsk,
                        const float* __restrict__ bias1,
                        const float* __restrict__ bn_w, const float* __restrict__ bn_b,
                        const float* __restrict__ bn_rm, const float* __restrict__ bn_rv,
                        const int* __restrict__ ei, int E,
                        unsigned short* __restrict__ xbf,
                        unsigned short* __restrict__ wcat1,  // 272 x 128
                        unsigned short* __restrict__ wcat2,  // 256 x 128
                        int* __restrict__ deg8, unsigned short* __restrict__ rpos,
                        float* __restrict__ bnS, float* __restrict__ bnT,
                        int n4x, int N) {
  const int W4 = 128 * 128 / 4;  // 4096
  const int S4 = 16 * 128 / 4;   // 512
  int i = blockIdx.x * blockDim.x + threadIdx.x;
  const float* src;
  unsigned short* dst;
  int j;
  if (i < n4x) { src = x; dst = xbf; j = i; }
  else {
    j = i - n4x;
    if (j < W4)               { src = wl1; dst = wcat1; }
    else if (j < 2 * W4)      { src = wr1; dst = wcat1 + 128 * 128; j -= W4; }
    else if (j < 3 * W4)      { src = wl2; dst = wcat2; j -= 2 * W4; }
    else if (j < 4 * W4)      { src = wr2; dst = wcat2 + 128 * 128; j -= 3 * W4; }
    else if (j < 4 * W4 + S4) { src = wsk; dst = wcat1 + 256 * 128; j -= 4 * W4; }
    else {
      j -= 4 * W4 + S4;
      if (j < 32) {
        for (int t = j * 4; t < j * 4 + 4; ++t) {
          float S = bn_w[t] * rsqrtf(bn_rv[t] + BN_EPS);
          bnS[t] = S;
          bnT[t] = (bias1[t] - bn_rm[t]) * S + bn_b[t];
        }
      } else {
        int e = j - 32;
        if (e < E) {
          int d = ei[E + e];
          int c = (int)(blockIdx.x & 7);  // same-residue blocks share an XCD -> L2-local atomics
          rpos[e] = (unsigned short)atomicAdd(&deg8[(size_t)c * N + d], 1);
        }
      }
      return;
    }
  }
  float4 v = ((const float4*)src)[j];
  ushort4 o;
  o.x = f2bf(v.x); o.y = f2bf(v.y); o.z = f2bf(v.z); o.w = f2bf(v.w);
  ((ushort4*)dst)[j] = o;
}

// ---------------- fused CSR scan: sum 8 copies + global scan (decoupled lookback) ----------------
// bsum[] zeroed; blocks publish aggregate+1 (0 = not ready) with device-scope release.
__global__ __launch_bounds__(1024)
void csr_scan(const int* __restrict__ deg8, int* __restrict__ meta,
              int* __restrict__ cbase8, int* bsum, int N) {
  __shared__ int wsum[16];
  __shared__ int sh_base;
  int b = blockIdx.x;
  int tid = threadIdx.x;
  int lane = tid & 63, wid = tid >> 6;
  int i0 = b * 4096 + tid * 4;

  int4 v[8];
#pragma unroll
  for (int c = 0; c < 8; ++c) {
    const int* p = deg8 + (size_t)c * N;
    v[c] = make_int4(0, 0, 0, 0);
    if (i0 + 3 < N) v[c] = *(const int4*)(p + i0);
    else if (i0 < N) {
      v[c].x = p[i0];
      if (i0 + 1 < N) v[c].y = p[i0 + 1];
      if (i0 + 2 < N) v[c].z = p[i0 + 2];
    }
  }
  int4 run = make_int4(0, 0, 0, 0);
#pragma unroll
  for (int c = 0; c < 8; ++c) {
    int4 t = v[c];
    v[c] = run;
    run.x += t.x; run.y += t.y; run.z += t.z; run.w += t.w;
  }
  int g1 = (run.x + 1) & ~1, g2 = (run.y + 1) & ~1, g3 = (run.z + 1) & ~1, g4 = (run.w + 1) & ~1;
  int s1 = g1, s2 = s1 + g2, s3 = s2 + g3, s4 = s3 + g4;
  int s = s4;
#pragma unroll
  for (int d = 1; d < 64; d <<= 1) { int t = __shfl_up(s, d, 64); if (lane >= d) s += t; }
  if (lane == 63) wsum[wid] = s;
  __syncthreads();
  if (tid < 16) {
    int ws = wsum[tid];
#pragma unroll
    for (int d = 1; d < 16; d <<= 1) { int t = __shfl_up(ws, d, 16); if (tid >= d) ws += t; }
    wsum[tid] = ws;
  }
  __syncthreads();
  if (tid == 0) {
    __hip_atomic_store(&bsum[b], wsum[15] + 1, __ATOMIC_RELEASE, __HIP_MEMORY_SCOPE_AGENT);
    int base = 0;
    for (int j = 0; j < b; ++j) {
      int x;
      do { x = __hip_atomic_load(&bsum[j], __ATOMIC_ACQUIRE, __HIP_MEMORY_SCOPE_AGENT); } while (x == 0);
      base += x - 1;
    }
    sh_base = base;
  }
  __syncthreads();
  int off = sh_base + (wid ? wsum[wid - 1] : 0) + (s - s4);
  int st[4] = {off, off + s1, off + s2, off + s3};
  int tv[4] = {run.x, run.y, run.z, run.w};
#pragma unroll
  for (int k = 0; k < 4; ++k)
    if (i0 + k < N) ((int2*)meta)[i0 + k] = make_int2(st[k], tv[k]);
#pragma unroll
  for (int c = 0; c < 8; ++c) {
    int* p = cbase8 + (size_t)c * N;
    if (i0 + 3 < N) {
      *(int4*)(p + i0) = make_int4(st[0] + v[c].x, st[1] + v[c].y, st[2] + v[c].z, st[3] + v[c].w);
    } else if (i0 < N) {
      p[i0] = st[0] + v[c].x;
      if (i0 + 1 < N) p[i0 + 1] = st[1] + v[c].y;
      if (i0 + 2 < N) p[i0 + 2] = st[2] + v[c].z;
    }
  }
}

// ---------------- HYBRID: scatter (latency-bound) + gemm1 (MFMA) in one dispatch ----------------
// Interleaved block roles so both are resident concurrently: first 2*min(S,G) blocks
// alternate scatter/gemm; remainder take the larger role.
__global__ __launch_bounds__(256)
void scatter_gemm(const int* __restrict__ ei, int E, int ebase,
                  const int* __restrict__ cbase8,
                  const unsigned short* __restrict__ rpos,
                  unsigned short* __restrict__ csr, int N, int SCB,
                  const unsigned short* __restrict__ A, const unsigned short* __restrict__ B,
                  const float* __restrict__ bias0, const float* __restrict__ bias1,
                  unsigned short* __restrict__ Cbf, float* __restrict__ Cf,
                  int M, int pstrips, int GMB) {
  int b = (int)blockIdx.x;
  int mn2 = 2 * min(SCB, GMB);
  bool isScatter;
  int id;
  if (b < mn2) { isScatter = (b & 1) == 0; id = b >> 1; }
  else { isScatter = SCB > GMB; id = (b - mn2) + min(SCB, GMB); }

  if (isScatter) {
    int e = id * 256 + (int)threadIdx.x;
    if (e < E) {
      int d = ei[E + e];
      int c = ((ebase + e) >> 8) & 7;  // counting block's residue, recomputed
      csr[cbase8[(size_t)c * N + d] + (int)rpos[e]] = (unsigned short)ei[e];
    }
    return;
  }

  int wave = id * 4 + (int)(threadIdx.x >> 6);
  int lane = threadIdx.x & 63;
  int mtiles = (M + 31) >> 5;
  if (wave >= mtiles * pstrips) return;
  int mt = wave % mtiles, ps = wave / mtiles;
  int r = lane & 15, quad = lane >> 4;

  const unsigned short* Abase = A + (size_t)(mt * 32 + r) * 128 + quad * 8;
  bf16x8 a0[4], a1[4];
#pragma unroll
  for (int k = 0; k < 4; ++k) {
    a0[k] = *(const bf16x8*)(Abase + 32 * k);
    a1[k] = *(const bf16x8*)(Abase + 16 * 128 + 32 * k);  // guarded at store
  }

  int row0 = mt * 32 + quad * 4;
  const int Ptot = 272;
#pragma unroll
  for (int pp = 0; pp < 4; ++pp) {
    int p0 = ps * 64 + pp * 16;
    if (p0 >= Ptot) break;
    const unsigned short* Bbase = B + (size_t)(p0 + r) * 128 + quad * 8;
    bf16x8 bfr[4];
#pragma unroll
    for (int k = 0; k < 4; ++k) bfr[k] = *(const bf16x8*)(Bbase + 32 * k);
    floatx4 acc0 = {0.f, 0.f, 0.f, 0.f};
    floatx4 acc1 = {0.f, 0.f, 0.f, 0.f};
#pragma unroll
    for (int k = 0; k < 4; ++k) {
      acc0 = __builtin_amdgcn_mfma_f32_16x16x32_bf16(a0[k], bfr[k], acc0, 0, 0, 0);
      acc1 = __builtin_amdgcn_mfma_f32_16x16x32_bf16(a1[k], bfr[k], acc1, 0, 0, 0);
    }
    int col = p0 + r;
    if (col >= 256) {
#pragma unroll
      for (int i = 0; i < 4; ++i) {
        if (row0 + i < M)      Cf[(size_t)(row0 + i) * 16 + (col - 256)] = acc0[i];
        if (row0 + 16 + i < M) Cf[(size_t)(row0 + 16 + i) * 16 + (col - 256)] = acc1[i];
      }
    } else {
      float bs = (col < 128) ? bias0[col] : bias1[col - 128];
#pragma unroll
      for (int i = 0; i < 4; ++i) {
        if (row0 + i < M)      Cbf[(size_t)(row0 + i) * 256 + col] = f2bf(acc0[i] + bs);
        if (row0 + 16 + i < M) Cbf[(size_t)(row0 + 16 + i) * 256 + col] = f2bf(acc1[i] + bs);
      }
    }
  }
}

// ---------------- plain bf16 MFMA GEMM (layer 2) ----------------
__global__ __launch_bounds__(256)
void gemm_bf16_mfma(const unsigned short* __restrict__ A, const unsigned short* __restrict__ B,
                    const float* __restrict__ bias0, const float* __restrict__ bias1,
                    unsigned short* __restrict__ Cbf, int M, int pstrips) {
  int wave = (int)((blockIdx.x * blockDim.x + threadIdx.x) >> 6);
  int lane = threadIdx.x & 63;
  int mtiles = (M + 31) >> 5;
  if (wave >= mtiles * pstrips) return;
  int mt = wave % mtiles, ps = wave / mtiles;
  int r = lane & 15, quad = lane >> 4;

  const unsigned short* Abase = A + (size_t)(mt * 32 + r) * 128 + quad * 8;
  bf16x8 a0[4], a1[4];
#pragma unroll
  for (int k = 0; k < 4; ++k) {
    a0[k] = *(const bf16x8*)(Abase + 32 * k);
    a1[k] = *(const bf16x8*)(Abase + 16 * 128 + 32 * k);
  }

  int row0 = mt * 32 + quad * 4;
#pragma unroll
  for (int pp = 0; pp < 4; ++pp) {
    int p0 = ps * 64 + pp * 16;
    const unsigned short* Bbase = B + (size_t)(p0 + r) * 128 + quad * 8;
    bf16x8 b[4];
#pragma unroll
    for (int k = 0; k < 4; ++k) b[k] = *(const bf16x8*)(Bbase + 32 * k);
    floatx4 acc0 = {0.f, 0.f, 0.f, 0.f};
    floatx4 acc1 = {0.f, 0.f, 0.f, 0.f};
#pragma unroll
    for (int k = 0; k < 4; ++k) {
      acc0 = __builtin_amdgcn_mfma_f32_16x16x32_bf16(a0[k], b[k], acc0, 0, 0, 0);
      acc1 = __builtin_amdgcn_mfma_f32_16x16x32_bf16(a1[k], b[k], acc1, 0, 0, 0);
    }
    int col = p0 + r;
    float bs = (col < 128) ? bias0[col] : bias1[col - 128];
#pragma unroll
    for (int i = 0; i < 4; ++i) {
      if (row0 + i < M)      Cbf[(size_t)(row0 + i) * 256 + col] = f2bf(acc0[i] + bs);
      if (row0 + 16 + i < M) Cbf[(size_t)(row0 + 16 + i) * 256 + col] = f2bf(acc1[i] + bs);
    }
  }
}

// ---------------- GATv2 aggregation: persistent waves, scalar indices ----------------
template <int LAYER>
__global__ __launch_bounds__(256)
void gat_agg(const unsigned int* __restrict__ xlr,
             const int* __restrict__ meta,  // int2 {start, deg} per dst
             const unsigned short* __restrict__ csr,
             const float* __restrict__ att,
             const float* __restrict__ p0, const float* __restrict__ p1,
             const float* __restrict__ p2, const float* __restrict__ p3,
             void* __restrict__ outp, int n, int nwaves) {
  int lane = threadIdx.x & 63;
  int gw = (int)((blockIdx.x * blockDim.x + threadIdx.x) >> 6);
  int half = lane >> 5, sl = lane & 31;
  float4 at = ((const float4*)att)[sl];
  const float SC = 0.6f * 1.44269504f;
  float a0 = SC * at.x, a1 = SC * at.y, a2 = SC * at.z, a3 = SC * at.w;

  for (int dst = gw; dst < n; dst += nwaves) {
    int dsts = __builtin_amdgcn_readfirstlane(dst);
    int2 m = *(const int2*)(meta + 2 * (size_t)dsts);
    int beg = __builtin_amdgcn_readfirstlane(m.x);
    int dg  = __builtin_amdgcn_readfirstlane(m.y);
    const unsigned* cp = (const unsigned*)csr + (beg >> 1);  // beg is even

    uint2 ur = *(const uint2*)(xlr + (size_t)dsts * 128 + 64 + sl * 2);
    float xr0 = bf_lo(ur.x), xr1 = bf_hi(ur.x), xr2 = bf_lo(ur.y), xr3 = bf_hi(ur.y);
    float lA = 0.f, lB = 0.f;
    float cA0 = 0.f, cA1 = 0.f, cA2 = 0.f, cA3 = 0.f;
    float cB0 = 0.f, cB1 = 0.f, cB2 = 0.f, cB3 = 0.f;

    auto body = [&](uint2 u, float vm, bool useB, bool masked) {
      float x0 = bf_lo(u.x), x1 = bf_hi(u.x), x2 = bf_lo(u.y), x3 = bf_hi(u.y);
      float e0 = x0 + xr0, e1 = x1 + xr1, e2 = x2 + xr2, e3 = x3 + xr3;
      float sc = fmaf(fmaf(fabsf(e0), 0.66666667f, e0), a0,
                 fmaf(fmaf(fabsf(e1), 0.66666667f, e1), a1,
                 fmaf(fmaf(fabsf(e2), 0.66666667f, e2), a2,
                      fmaf(fabsf(e3), 0.66666667f, e3) * a3)));
      sc += __shfl_xor(sc, 1);
      sc += __shfl_xor(sc, 2);        // per-head score (4 lanes = 16 ch)
      float pw = EXP2F(sc);
      if (masked) pw *= vm;
      if (useB) {
        lB += pw;
        cB0 = fmaf(pw, x0, cB0); cB1 = fmaf(pw, x1, cB1);
        cB2 = fmaf(pw, x2, cB2); cB3 = fmaf(pw, x3, cB3);
      } else {
        lA += pw;
        cA0 = fmaf(pw, x0, cA0); cA1 = fmaf(pw, x1, cA1);
        cA2 = fmaf(pw, x2, cA2); cA3 = fmaf(pw, x3, cA3);
      }
    };

    int npm = dg >> 1;        // full (unmasked) pairs
    int npm4 = npm & ~3;
    int p = 0;
    for (; p < npm4; p += 4) {
      uint2 u[4];
#pragma unroll
      for (int k = 0; k < 4; ++k) {
        unsigned pr = cp[p + k];      // scalar s_load
        int s = half ? (int)(pr >> 16) : (int)(pr & 0xFFFFu);
        u[k] = *(const uint2*)(xlr + ((size_t)s << 7) + sl * 2);
      }
#pragma unroll
      for (int k = 0; k < 4; ++k) body(u[k], 1.f, k & 1, false);
    }
    {  // masked final group: slots 2p..2p+7 cover remaining edges + self-loop (slot dg)
      int tot = dg + 1;
      uint2 u[4];
      float vm[4];
#pragma unroll
      for (int k = 0; k < 4; ++k) {
        unsigned pr = cp[p + k];      // may over-read into slack; masked below
        int e0 = 2 * (p + k), e1 = e0 + 1;
        int sA = (e0 < dg) ? (int)(pr & 0xFFFFu) : dsts;
        int sB = (e1 < dg) ? (int)(pr >> 16) : dsts;
        float mA = (e0 < tot) ? 1.f : 0.f;
        float mB = (e1 < tot) ? 1.f : 0.f;
        int s = half ? sB : sA;
        vm[k] = half ? mB : mA;
        u[k] = *(const uint2*)(xlr + ((size_t)s << 7) + sl * 2);
      }
#pragma unroll
      for (int k = 0; k < 4; ++k) body(u[k], vm[k], k & 1, true);
    }

    float l = lA + lB;
    float c0 = cA0 + cB0, c1 = cA1 + cB1, c2 = cA2 + cB2, c3 = cA3 + cB3;
    l  += __shfl_xor(l, 32);
    c0 += __shfl_xor(c0, 32); c1 += __shfl_xor(c1, 32);
    c2 += __shfl_xor(c2, 32); c3 += __shfl_xor(c3, 32);
    float inv = 1.f / l;

    if (LAYER == 1) {
      float4 S = ((const float4*)p0)[sl];
      float4 T = ((const float4*)p1)[sl];
      float o0 = fmaf(c0 * inv, S.x, T.x);
      float o1 = fmaf(c1 * inv, S.y, T.y);
      float o2 = fmaf(c2 * inv, S.z, T.z);
      float o3 = fmaf(c3 * inv, S.w, T.w);
      o0 = (o0 > 0.f) ? o0 : (__expf(o0) - 1.f);
      o1 = (o1 > 0.f) ? o1 : (__expf(o1) - 1.f);
      o2 = (o2 > 0.f) ? o2 : (__expf(o2) - 1.f);
      o3 = (o3 > 0.f) ? o3 : (__expf(o3) - 1.f);
      if (half == 0) {
        uint2 o;
        o.x = ((unsigned)f2bf(o1) << 16) | f2bf(o0);
        o.y = ((unsigned)f2bf(o3) << 16) | f2bf(o2);
        ((uint2*)outp)[(size_t)dst * 32 + sl] = o;
      }
    } else {
      float y0 = c0 * inv, y1 = c1 * inv, y2 = c2 * inv, y3 = c3 * inv;
#pragma unroll
      for (int d = 4; d <= 16; d <<= 1) {
        y0 += __shfl_xor(y0, d); y1 += __shfl_xor(y1, d);
        y2 += __shfl_xor(y2, d); y3 += __shfl_xor(y3, d);
      }
      int chh = (sl & 3) * 4;
      float4 b2 = *(const float4*)(p1 + chh);
      float4 xs = *(const float4*)(p0 + (size_t)dst * 16 + chh);
      y0 = y0 * 0.125f + b2.x + xs.x;
      y1 = y1 * 0.125f + b2.y + xs.y;
      y2 = y2 * 0.125f + b2.z + xs.z;
      y3 = y3 * 0.125f + b2.w + xs.w;
      float t = (y0 + y1) + (y2 + y3);
      t += __shfl_xor(t, 1); t += __shfl_xor(t, 2);
      float mu = t * (1.f / 16.f);
      float d0 = y0 - mu, d1 = y1 - mu, d2 = y2 - mu, d3 = y3 - mu;
      float v = (d0 * d0 + d1 * d1) + (d2 * d2 + d3 * d3);
      v += __shfl_xor(v, 1); v += __shfl_xor(v, 2);
      float istd = rsqrtf(v * (1.f / 16.f) + LN_EPS);
      float4 lw = *(const float4*)(p2 + chh);
      float4 lb = *(const float4*)(p3 + chh);
      if (lane < 4) {
        float4 o;
        o.x = d0 * istd * lw.x + lb.x;
        o.y = d1 * istd * lw.y + lb.y;
        o.z = d2 * istd * lw.z + lb.z;
        o.w = d3 * istd * lw.w + lb.w;
        *(float4*)((float*)outp + (size_t)dst * 16 + chh) = o;
      }
    }
  }
}

extern "C" void kernel_launch(void* const* d_in, const int* in_sizes, int n_in,
                              void* d_out, int out_size, void* d_ws, size_t ws_size,
                              hipStream_t stream) {
  const float* x     = (const float*)d_in[0];
  const int*   ei    = (const int*)d_in[1];
  const float* Wl1   = (const float*)d_in[2];
  const float* bl1   = (const float*)d_in[3];
  const float* Wr1   = (const float*)d_in[4];
  const float* br1   = (const float*)d_in[5];
  const float* att1  = (const float*)d_in[6];
  const float* bias1 = (const float*)d_in[7];
  const float* bn_w  = (const float*)d_in[8];
  const float* bn_b  = (const float*)d_in[9];
  const float* bn_rm = (const float*)d_in[10];
  const float* bn_rv = (const float*)d_in[11];
  const float* Wl2   = (const float*)d_in[12];
  const float* bl2   = (const float*)d_in[13];
  const float* Wr2   = (const float*)d_in[14];
  const float* br2   = (const float*)d_in[15];
  const float* att2  = (const float*)d_in[16];
  const float* bias2 = (const float*)d_in[17];
  const float* Wskip = (const float*)d_in[18];
  const float* ln_w  = (const float*)d_in[19];
  const float* ln_b  = (const float*)d_in[20];

  const int N = in_sizes[0] / 128;  // 50000
  const int E = in_sizes[1] / 2;    // 800000

  char* w = (char*)d_ws;
  size_t off = 0;
  auto alloc = [&](size_t bytes) -> void* {
    void* p = (void*)(w + off);
    off += (bytes + 255) & ~(size_t)255;
    return p;
  };
  unsigned short* xbf    = (unsigned short*)alloc((size_t)N * 128 * 2);
  unsigned short* wcat1  = (unsigned short*)alloc(272 * 128 * 2);  // [Wl1|Wr1|Wskip]
  unsigned short* wcat2  = (unsigned short*)alloc(256 * 128 * 2);  // [Wl2|Wr2]
  unsigned int*   xlr    = (unsigned int*)alloc((size_t)N * 128 * 4);  // bf16 [N,256]
  float*          xres   = (float*)alloc((size_t)N * 16 * 4);
  unsigned short* hbf    = (unsigned short*)alloc((size_t)N * 128 * 2);
  float*          bnS    = (float*)alloc(128 * 4);
  float*          bnT    = (float*)alloc(128 * 4);
  int*            deg8   = (int*)alloc((size_t)8 * N * 4);   // privatized counters (zeroed)
  int*            bsum   = (int*)alloc(64 * 4);              // lookback aggregates (zeroed, +1 sentinel)
  int*            cbase8 = (int*)alloc((size_t)8 * N * 4);   // per-copy segment bases
  int*            meta   = (int*)alloc((size_t)2 * N * 4);   // {start, deg} per dst
  unsigned short* rpos   = (unsigned short*)alloc((size_t)E * 2);
  unsigned short* csr    = (unsigned short*)alloc((size_t)(E + N) * 2 + 256);  // even-padded

  const int n4x = (N * 128) / 4;
  const int W4 = 128 * 128 / 4, S4 = 16 * 128 / 4;
  const int ebase = n4x + 4 * W4 + S4 + 32;  // thread index of edge 0 in cvt_all
  const int nb = (N + 4095) / 4096;          // csr_scan blocks (13)

  // --- one memset covers deg8 + bsum (contiguous in ws) ---
  hipMemsetAsync(deg8, 0, (size_t)8 * N * 4 + 256 + 64 * 4, stream);
  {
    int tot = ebase + E;
    cvt_all<<<(tot + 255) / 256, 256, 0, stream>>>(
        x, Wl1, Wr1, Wl2, Wr2, Wskip, bias1, bn_w, bn_b, bn_rm, bn_rv, ei, E,
        xbf, wcat1, wcat2, deg8, rpos, bnS, bnT, n4x, N);
  }

  // --- CSR scan (decoupled lookback) ---
  csr_scan<<<nb, 1024, 0, stream>>>(deg8, meta, cbase8, bsum, N);

  // --- HYBRID: scatter + layer-1 GEMM concurrently ---
  {
    int SCB = (E + 255) / 256;                    // scatter blocks
    int mtiles = (N + 31) >> 5;
    int GMB = (mtiles * 5 + 3) / 4;               // gemm blocks
    scatter_gemm<<<SCB + GMB, 256, 0, stream>>>(
        ei, E, ebase, cbase8, rpos, csr, N, SCB,
        xbf, wcat1, bl1, br1, (unsigned short*)xlr, xres, N, 5, GMB);
  }

  // --- layer 1 aggregation -> packed bf16 h ---
  {
    int blocks = 2048, nwaves = blocks * 4;
    gat_agg<1><<<blocks, 256, 0, stream>>>(xlr, meta, csr, att1,
                                           bnS, bnT, nullptr, nullptr, (void*)hbf, N, nwaves);
  }

  // --- layer 2: [xl|xr] = h @ [Wl2|Wr2]^T ---
  {
    int mtiles = (N + 31) >> 5;
    int waves = mtiles * 4;
    gemm_bf16_mfma<<<(waves + 3) / 4, 256, 0, stream>>>(
        hbf, wcat2, bl2, br2, (unsigned short*)xlr, N, 4);
  }

  // --- layer 2 aggregation -> out ---
  {
    int blocks = 2048, nwaves = blocks * 4;
    gat_agg<2><<<blocks, 256, 0, stream>>>(xlr, meta, csr, att2,
                                           xres, bias2, ln_w, ln_b, d_out, N, nwaves);
  }
}

// Round 12
// 305.931 us; speedup vs baseline: 1.0253x; 1.0253x over previous
//
#include <hip/hip_runtime.h>

#define NEG_SLOPE 0.2f
#define BN_EPS 1e-5f
#define LN_EPS 1e-5f

#if __has_builtin(__builtin_amdgcn_exp2f)
#define EXP2F(x) __builtin_amdgcn_exp2f(x)
#else
#define EXP2F(x) exp2f(x)
#endif

typedef __bf16 bf16_t;
typedef bf16_t bf16x8 __attribute__((ext_vector_type(8)));
typedef float floatx4 __attribute__((ext_vector_type(4)));

__device__ __forceinline__ unsigned short f2bf(float f) {
  unsigned u = __float_as_uint(f);
  u += 0x7FFFu + ((u >> 16) & 1u);
  return (unsigned short)(u >> 16);
}
__device__ __forceinline__ float bf_lo(unsigned u) { return __uint_as_float(u << 16); }
__device__ __forceinline__ float bf_hi(unsigned u) { return __uint_as_float(u & 0xFFFF0000u); }

// ---------------- fused: conversions + BN fold + XCD-privatized degree count ----------------
__global__ void cvt_all(const float* __restrict__ x,
                        const float* __restrict__ wl1, const float* __restrict__ wr1,
                        const float* __restrict__ wl2, const float* __restrict__ wr2,
                        const float* __restrict__ wsk,
                        const float* __restrict__ bias1,
                        const float* __restrict__ bn_w, const float* __restrict__ bn_b,
                        const float* __restrict__ bn_rm, const float* __restrict__ bn_rv,
                        const int* __restrict__ ei, int E,
                        unsigned short* __restrict__ xbf,
                        unsigned short* __restrict__ wcat1,  // 272 x 128
                        unsigned short* __restrict__ wcat2,  // 256 x 128
                        int* __restrict__ deg8, unsigned short* __restrict__ rpos,
                        float* __restrict__ bnS, float* __restrict__ bnT,
                        int n4x, int N) {
  const int W4 = 128 * 128 / 4;  // 4096
  const int S4 = 16 * 128 / 4;   // 512
  int i = blockIdx.x * blockDim.x + threadIdx.x;
  const float* src;
  unsigned short* dst;
  int j;
  if (i < n4x) { src = x; dst = xbf; j = i; }
  else {
    j = i - n4x;
    if (j < W4)               { src = wl1; dst = wcat1; }
    else if (j < 2 * W4)      { src = wr1; dst = wcat1 + 128 * 128; j -= W4; }
    else if (j < 3 * W4)      { src = wl2; dst = wcat2; j -= 2 * W4; }
    else if (j < 4 * W4)      { src = wr2; dst = wcat2 + 128 * 128; j -= 3 * W4; }
    else if (j < 4 * W4 + S4) { src = wsk; dst = wcat1 + 256 * 128; j -= 4 * W4; }
    else {
      j -= 4 * W4 + S4;
      if (j < 32) {
        for (int t = j * 4; t < j * 4 + 4; ++t) {
          float S = bn_w[t] * rsqrtf(bn_rv[t] + BN_EPS);
          bnS[t] = S;
          bnT[t] = (bias1[t] - bn_rm[t]) * S + bn_b[t];
        }
      } else {
        int e = j - 32;
        if (e < E) {
          int d = ei[E + e];
          int c = (int)(blockIdx.x & 7);  // same-residue blocks share an XCD -> L2-local atomics
          rpos[e] = (unsigned short)atomicAdd(&deg8[(size_t)c * N + d], 1);
        }
      }
      return;
    }
  }
  float4 v = ((const float4*)src)[j];
  ushort4 o;
  o.x = f2bf(v.x); o.y = f2bf(v.y); o.z = f2bf(v.z); o.w = f2bf(v.w);
  ((ushort4*)dst)[j] = o;
}

// ---------------- fused CSR scan: sum 8 copies + global scan (decoupled lookback) ----------------
// bsum[] zeroed; blocks publish aggregate+1 (0 = not ready) with device-scope release.
__global__ __launch_bounds__(1024)
void csr_scan(const int* __restrict__ deg8, int* __restrict__ meta,
              int* __restrict__ cbase8, int* bsum, int N) {
  __shared__ int wsum[16];
  __shared__ int sh_base;
  int b = blockIdx.x;
  int tid = threadIdx.x;
  int lane = tid & 63, wid = tid >> 6;
  int i0 = b * 4096 + tid * 4;

  int4 v[8];
#pragma unroll
  for (int c = 0; c < 8; ++c) {
    const int* p = deg8 + (size_t)c * N;
    v[c] = make_int4(0, 0, 0, 0);
    if (i0 + 3 < N) v[c] = *(const int4*)(p + i0);
    else if (i0 < N) {
      v[c].x = p[i0];
      if (i0 + 1 < N) v[c].y = p[i0 + 1];
      if (i0 + 2 < N) v[c].z = p[i0 + 2];
    }
  }
  int4 run = make_int4(0, 0, 0, 0);
#pragma unroll
  for (int c = 0; c < 8; ++c) {
    int4 t = v[c];
    v[c] = run;
    run.x += t.x; run.y += t.y; run.z += t.z; run.w += t.w;
  }
  int g1 = (run.x + 1) & ~1, g2 = (run.y + 1) & ~1, g3 = (run.z + 1) & ~1, g4 = (run.w + 1) & ~1;
  int s1 = g1, s2 = s1 + g2, s3 = s2 + g3, s4 = s3 + g4;
  int s = s4;
#pragma unroll
  for (int d = 1; d < 64; d <<= 1) { int t = __shfl_up(s, d, 64); if (lane >= d) s += t; }
  if (lane == 63) wsum[wid] = s;
  __syncthreads();
  if (tid < 16) {
    int ws = wsum[tid];
#pragma unroll
    for (int d = 1; d < 16; d <<= 1) { int t = __shfl_up(ws, d, 16); if (tid >= d) ws += t; }
    wsum[tid] = ws;
  }
  __syncthreads();
  if (tid == 0) {
    __hip_atomic_store(&bsum[b], wsum[15] + 1, __ATOMIC_RELEASE, __HIP_MEMORY_SCOPE_AGENT);
    int base = 0;
    for (int j = 0; j < b; ++j) {
      int x;
      do { x = __hip_atomic_load(&bsum[j], __ATOMIC_ACQUIRE, __HIP_MEMORY_SCOPE_AGENT); } while (x == 0);
      base += x - 1;
    }
    sh_base = base;
  }
  __syncthreads();
  int off = sh_base + (wid ? wsum[wid - 1] : 0) + (s - s4);
  int st[4] = {off, off + s1, off + s2, off + s3};
  int tv[4] = {run.x, run.y, run.z, run.w};
#pragma unroll
  for (int k = 0; k < 4; ++k)
    if (i0 + k < N) ((int2*)meta)[i0 + k] = make_int2(st[k], tv[k]);
#pragma unroll
  for (int c = 0; c < 8; ++c) {
    int* p = cbase8 + (size_t)c * N;
    if (i0 + 3 < N) {
      *(int4*)(p + i0) = make_int4(st[0] + v[c].x, st[1] + v[c].y, st[2] + v[c].z, st[3] + v[c].w);
    } else if (i0 < N) {
      p[i0] = st[0] + v[c].x;
      if (i0 + 1 < N) p[i0 + 1] = st[1] + v[c].y;
      if (i0 + 2 < N) p[i0 + 2] = st[2] + v[c].z;
    }
  }
}

// ---------------- scatter (atomic-free, 1 edge/thread) ----------------
__global__ void scatter_edges(const int* __restrict__ ei, int E, int ebase,
                              const int* __restrict__ cbase8,
                              const unsigned short* __restrict__ rpos,
                              unsigned short* __restrict__ csr, int N) {
  int e = blockIdx.x * blockDim.x + threadIdx.x;
  if (e < E) {
    int d = ei[E + e];
    int c = ((ebase + e) >> 8) & 7;  // counting block's residue, recomputed
    csr[cbase8[(size_t)c * N + d] + (int)rpos[e]] = (unsigned short)ei[e];
  }
}

// ---------------- bf16 MFMA GEMM:  C = A[M,128] * B[P,128]^T + bias ----------------
template <bool MIXED>
__global__ __launch_bounds__(256)
void gemm_bf16_mfma(const unsigned short* __restrict__ A, const unsigned short* __restrict__ B,
                    const float* __restrict__ bias0, const float* __restrict__ bias1,
                    unsigned short* __restrict__ Cbf, float* __restrict__ Cf,
                    int M, int pstrips) {
  int wave = (int)((blockIdx.x * blockDim.x + threadIdx.x) >> 6);
  int lane = threadIdx.x & 63;
  int mtiles = (M + 31) >> 5;
  if (wave >= mtiles * pstrips) return;
  int mt = wave % mtiles, ps = wave / mtiles;
  int r = lane & 15, quad = lane >> 4;

  const unsigned short* Abase = A + (size_t)(mt * 32 + r) * 128 + quad * 8;
  bf16x8 a0[4], a1[4];
#pragma unroll
  for (int k = 0; k < 4; ++k) {
    a0[k] = *(const bf16x8*)(Abase + 32 * k);
    a1[k] = *(const bf16x8*)(Abase + 16 * 128 + 32 * k);  // guarded at store
  }

  int row0 = mt * 32 + quad * 4;
  const int Ptot = MIXED ? 272 : 256;
#pragma unroll
  for (int pp = 0; pp < 4; ++pp) {
    int p0 = ps * 64 + pp * 16;
    if (p0 >= Ptot) break;
    const unsigned short* Bbase = B + (size_t)(p0 + r) * 128 + quad * 8;
    bf16x8 b[4];
#pragma unroll
    for (int k = 0; k < 4; ++k) b[k] = *(const bf16x8*)(Bbase + 32 * k);
    floatx4 acc0 = {0.f, 0.f, 0.f, 0.f};
    floatx4 acc1 = {0.f, 0.f, 0.f, 0.f};
#pragma unroll
    for (int k = 0; k < 4; ++k) {
      acc0 = __builtin_amdgcn_mfma_f32_16x16x32_bf16(a0[k], b[k], acc0, 0, 0, 0);
      acc1 = __builtin_amdgcn_mfma_f32_16x16x32_bf16(a1[k], b[k], acc1, 0, 0, 0);
    }
    int col = p0 + r;
    if (MIXED && col >= 256) {
#pragma unroll
      for (int i = 0; i < 4; ++i) {
        if (row0 + i < M)      Cf[(size_t)(row0 + i) * 16 + (col - 256)] = acc0[i];
        if (row0 + 16 + i < M) Cf[(size_t)(row0 + 16 + i) * 16 + (col - 256)] = acc1[i];
      }
    } else {
      float bs = (col < 128) ? bias0[col] : bias1[col - 128];
#pragma unroll
      for (int i = 0; i < 4; ++i) {
        if (row0 + i < M)      Cbf[(size_t)(row0 + i) * 256 + col] = f2bf(acc0[i] + bs);
        if (row0 + 16 + i < M) Cbf[(size_t)(row0 + 16 + i) * 256 + col] = f2bf(acc1[i] + bs);
      }
    }
  }
}

// ---------------- GATv2 aggregation: persistent waves, scalar indices, 8-deep MLP ----------------
// Main loop: 8 csr pairs (16 edges) per group, all 8 gathers in flight before math.
// Then one unmasked 4-group if >=4 pairs remain, then ONE masked 4-group covering the
// remaining pairs + odd edge + self-loop (8 slots always suffice: <=3 pairs + odd + self).
template <int LAYER>
__global__ __launch_bounds__(256)
void gat_agg(const unsigned int* __restrict__ xlr,
             const int* __restrict__ meta,  // int2 {start, deg} per dst
             const unsigned short* __restrict__ csr,
             const float* __restrict__ att,
             const float* __restrict__ p0, const float* __restrict__ p1,
             const float* __restrict__ p2, const float* __restrict__ p3,
             void* __restrict__ outp, int n, int nwaves) {
  int lane = threadIdx.x & 63;
  int gw = (int)((blockIdx.x * blockDim.x + threadIdx.x) >> 6);
  int half = lane >> 5, sl = lane & 31;
  float4 at = ((const float4*)att)[sl];
  const float SC = 0.6f * 1.44269504f;
  float a0 = SC * at.x, a1 = SC * at.y, a2 = SC * at.z, a3 = SC * at.w;

  for (int dst = gw; dst < n; dst += nwaves) {
    int dsts = __builtin_amdgcn_readfirstlane(dst);
    int2 m = *(const int2*)(meta + 2 * (size_t)dsts);
    int beg = __builtin_amdgcn_readfirstlane(m.x);
    int dg  = __builtin_amdgcn_readfirstlane(m.y);
    const unsigned* cp = (const unsigned*)csr + (beg >> 1);  // beg is even

    uint2 ur = *(const uint2*)(xlr + (size_t)dsts * 128 + 64 + sl * 2);
    float xr0 = bf_lo(ur.x), xr1 = bf_hi(ur.x), xr2 = bf_lo(ur.y), xr3 = bf_hi(ur.y);
    float lA = 0.f, lB = 0.f;
    float cA0 = 0.f, cA1 = 0.f, cA2 = 0.f, cA3 = 0.f;
    float cB0 = 0.f, cB1 = 0.f, cB2 = 0.f, cB3 = 0.f;

    auto body = [&](uint2 u, float vm, bool useB, bool masked) {
      float x0 = bf_lo(u.x), x1 = bf_hi(u.x), x2 = bf_lo(u.y), x3 = bf_hi(u.y);
      float e0 = x0 + xr0, e1 = x1 + xr1, e2 = x2 + xr2, e3 = x3 + xr3;
      float sc = fmaf(fmaf(fabsf(e0), 0.66666667f, e0), a0,
                 fmaf(fmaf(fabsf(e1), 0.66666667f, e1), a1,
                 fmaf(fmaf(fabsf(e2), 0.66666667f, e2), a2,
                      fmaf(fabsf(e3), 0.66666667f, e3) * a3)));
      sc += __shfl_xor(sc, 1);
      sc += __shfl_xor(sc, 2);        // per-head score (4 lanes = 16 ch)
      float pw = EXP2F(sc);
      if (masked) pw *= vm;
      if (useB) {
        lB += pw;
        cB0 = fmaf(pw, x0, cB0); cB1 = fmaf(pw, x1, cB1);
        cB2 = fmaf(pw, x2, cB2); cB3 = fmaf(pw, x3, cB3);
      } else {
        lA += pw;
        cA0 = fmaf(pw, x0, cA0); cA1 = fmaf(pw, x1, cA1);
        cA2 = fmaf(pw, x2, cA2); cA3 = fmaf(pw, x3, cA3);
      }
    };

    int npm = dg >> 1;        // full (unmasked) pairs
    int p = 0;
    int npm8 = npm & ~7;
    for (; p < npm8; p += 8) {
      uint2 u[8];
#pragma unroll
      for (int k = 0; k < 8; ++k) {
        unsigned pr = cp[p + k];      // scalar s_load
        int s = half ? (int)(pr >> 16) : (int)(pr & 0xFFFFu);
        u[k] = *(const uint2*)(xlr + ((size_t)s << 7) + sl * 2);
      }
#pragma unroll
      for (int k = 0; k < 8; ++k) body(u[k], 1.f, k & 1, false);
    }
    if (npm - p >= 4) {
      uint2 u[4];
#pragma unroll
      for (int k = 0; k < 4; ++k) {
        unsigned pr = cp[p + k];
        int s = half ? (int)(pr >> 16) : (int)(pr & 0xFFFFu);
        u[k] = *(const uint2*)(xlr + ((size_t)s << 7) + sl * 2);
      }
#pragma unroll
      for (int k = 0; k < 4; ++k) body(u[k], 1.f, k & 1, false);
      p += 4;
    }
    {  // masked final group: slots 2p..2p+7 cover remaining edges + self-loop (slot dg)
      int tot = dg + 1;
      uint2 u[4];
      float vm[4];
#pragma unroll
      for (int k = 0; k < 4; ++k) {
        unsigned pr = cp[p + k];      // may over-read into slack; masked below
        int e0 = 2 * (p + k), e1 = e0 + 1;
        int sA = (e0 < dg) ? (int)(pr & 0xFFFFu) : dsts;
        int sB = (e1 < dg) ? (int)(pr >> 16) : dsts;
        float mA = (e0 < tot) ? 1.f : 0.f;
        float mB = (e1 < tot) ? 1.f : 0.f;
        int s = half ? sB : sA;
        vm[k] = half ? mB : mA;
        u[k] = *(const uint2*)(xlr + ((size_t)s << 7) + sl * 2);
      }
#pragma unroll
      for (int k = 0; k < 4; ++k) body(u[k], vm[k], k & 1, true);
    }

    float l = lA + lB;
    float c0 = cA0 + cB0, c1 = cA1 + cB1, c2 = cA2 + cB2, c3 = cA3 + cB3;
    l  += __shfl_xor(l, 32);
    c0 += __shfl_xor(c0, 32); c1 += __shfl_xor(c1, 32);
    c2 += __shfl_xor(c2, 32); c3 += __shfl_xor(c3, 32);
    float inv = 1.f / l;

    if (LAYER == 1) {
      float4 S = ((const float4*)p0)[sl];
      float4 T = ((const float4*)p1)[sl];
      float o0 = fmaf(c0 * inv, S.x, T.x);
      float o1 = fmaf(c1 * inv, S.y, T.y);
      float o2 = fmaf(c2 * inv, S.z, T.z);
      float o3 = fmaf(c3 * inv, S.w, T.w);
      o0 = (o0 > 0.f) ? o0 : (__expf(o0) - 1.f);
      o1 = (o1 > 0.f) ? o1 : (__expf(o1) - 1.f);
      o2 = (o2 > 0.f) ? o2 : (__expf(o2) - 1.f);
      o3 = (o3 > 0.f) ? o3 : (__expf(o3) - 1.f);
      if (half == 0) {
        uint2 o;
        o.x = ((unsigned)f2bf(o1) << 16) | f2bf(o0);
        o.y = ((unsigned)f2bf(o3) << 16) | f2bf(o2);
        ((uint2*)outp)[(size_t)dst * 32 + sl] = o;
      }
    } else {
      float y0 = c0 * inv, y1 = c1 * inv, y2 = c2 * inv, y3 = c3 * inv;
#pragma unroll
      for (int d = 4; d <= 16; d <<= 1) {
        y0 += __shfl_xor(y0, d); y1 += __shfl_xor(y1, d);
        y2 += __shfl_xor(y2, d); y3 += __shfl_xor(y3, d);
      }
      int chh = (sl & 3) * 4;
      float4 b2 = *(const float4*)(p1 + chh);
      float4 xs = *(const float4*)(p0 + (size_t)dst * 16 + chh);
      y0 = y0 * 0.125f + b2.x + xs.x;
      y1 = y1 * 0.125f + b2.y + xs.y;
      y2 = y2 * 0.125f + b2.z + xs.z;
      y3 = y3 * 0.125f + b2.w + xs.w;
      float t = (y0 + y1) + (y2 + y3);
      t += __shfl_xor(t, 1); t += __shfl_xor(t, 2);
      float mu = t * (1.f / 16.f);
      float d0 = y0 - mu, d1 = y1 - mu, d2 = y2 - mu, d3 = y3 - mu;
      float v = (d0 * d0 + d1 * d1) + (d2 * d2 + d3 * d3);
      v += __shfl_xor(v, 1); v += __shfl_xor(v, 2);
      float istd = rsqrtf(v * (1.f / 16.f) + LN_EPS);
      float4 lw = *(const float4*)(p2 + chh);
      float4 lb = *(const float4*)(p3 + chh);
      if (lane < 4) {
        float4 o;
        o.x = d0 * istd * lw.x + lb.x;
        o.y = d1 * istd * lw.y + lb.y;
        o.z = d2 * istd * lw.z + lb.z;
        o.w = d3 * istd * lw.w + lb.w;
        *(float4*)((float*)outp + (size_t)dst * 16 + chh) = o;
      }
    }
  }
}

extern "C" void kernel_launch(void* const* d_in, const int* in_sizes, int n_in,
                              void* d_out, int out_size, void* d_ws, size_t ws_size,
                              hipStream_t stream) {
  const float* x     = (const float*)d_in[0];
  const int*   ei    = (const int*)d_in[1];
  const float* Wl1   = (const float*)d_in[2];
  const float* bl1   = (const float*)d_in[3];
  const float* Wr1   = (const float*)d_in[4];
  const float* br1   = (const float*)d_in[5];
  const float* att1  = (const float*)d_in[6];
  const float* bias1 = (const float*)d_in[7];
  const float* bn_w  = (const float*)d_in[8];
  const float* bn_b  = (const float*)d_in[9];
  const float* bn_rm = (const float*)d_in[10];
  const float* bn_rv = (const float*)d_in[11];
  const float* Wl2   = (const float*)d_in[12];
  const float* bl2   = (const float*)d_in[13];
  const float* Wr2   = (const float*)d_in[14];
  const float* br2   = (const float*)d_in[15];
  const float* att2  = (const float*)d_in[16];
  const float* bias2 = (const float*)d_in[17];
  const float* Wskip = (const float*)d_in[18];
  const float* ln_w  = (const float*)d_in[19];
  const float* ln_b  = (const float*)d_in[20];

  const int N = in_sizes[0] / 128;  // 50000
  const int E = in_sizes[1] / 2;    // 800000

  char* w = (char*)d_ws;
  size_t off = 0;
  auto alloc = [&](size_t bytes) -> void* {
    void* p = (void*)(w + off);
    off += (bytes + 255) & ~(size_t)255;
    return p;
  };
  unsigned short* xbf    = (unsigned short*)alloc((size_t)N * 128 * 2);
  unsigned short* wcat1  = (unsigned short*)alloc(272 * 128 * 2);  // [Wl1|Wr1|Wskip]
  unsigned short* wcat2  = (unsigned short*)alloc(256 * 128 * 2);  // [Wl2|Wr2]
  unsigned int*   xlr    = (unsigned int*)alloc((size_t)N * 128 * 4);  // bf16 [N,256]
  float*          xres   = (float*)alloc((size_t)N * 16 * 4);
  unsigned short* hbf    = (unsigned short*)alloc((size_t)N * 128 * 2);
  float*          bnS    = (float*)alloc(128 * 4);
  float*          bnT    = (float*)alloc(128 * 4);
  int*            deg8   = (int*)alloc((size_t)8 * N * 4);   // privatized counters (zeroed)
  int*            bsum   = (int*)alloc(64 * 4);              // lookback aggregates (zeroed, +1 sentinel)
  int*            cbase8 = (int*)alloc((size_t)8 * N * 4);   // per-copy segment bases
  int*            meta   = (int*)alloc((size_t)2 * N * 4);   // {start, deg} per dst
  unsigned short* rpos   = (unsigned short*)alloc((size_t)E * 2);
  unsigned short* csr    = (unsigned short*)alloc((size_t)(E + N) * 2 + 256);  // even-padded

  const int n4x = (N * 128) / 4;
  const int W4 = 128 * 128 / 4, S4 = 16 * 128 / 4;
  const int ebase = n4x + 4 * W4 + S4 + 32;  // thread index of edge 0 in cvt_all
  const int nb = (N + 4095) / 4096;          // csr_scan blocks (13)

  // --- one memset covers deg8 + bsum (contiguous in ws) ---
  hipMemsetAsync(deg8, 0, (size_t)8 * N * 4 + 256 + 64 * 4, stream);
  {
    int tot = ebase + E;
    cvt_all<<<(tot + 255) / 256, 256, 0, stream>>>(
        x, Wl1, Wr1, Wl2, Wr2, Wskip, bias1, bn_w, bn_b, bn_rm, bn_rv, ei, E,
        xbf, wcat1, wcat2, deg8, rpos, bnS, bnT, n4x, N);
  }

  // --- CSR: fused sum+scan+bases (decoupled lookback), then atomic-free scatter ---
  csr_scan<<<nb, 1024, 0, stream>>>(deg8, meta, cbase8, bsum, N);
  scatter_edges<<<(E + 255) / 256, 256, 0, stream>>>(ei, E, ebase, cbase8, rpos, csr, N);

  // --- layer 1: [xl|xr|xres] = x @ [Wl1|Wr1|Wskip]^T ---
  {
    int mtiles = (N + 31) >> 5;
    int waves = mtiles * 5;
    gemm_bf16_mfma<true><<<(waves + 3) / 4, 256, 0, stream>>>(
        xbf, wcat1, bl1, br1, (unsigned short*)xlr, xres, N, 5);
  }

  // --- layer 1 aggregation -> packed bf16 h ---
  {
    int blocks = 2048, nwaves = blocks * 4;
    gat_agg<1><<<blocks, 256, 0, stream>>>(xlr, meta, csr, att1,
                                           bnS, bnT, nullptr, nullptr, (void*)hbf, N, nwaves);
  }

  // --- layer 2: [xl|xr] = h @ [Wl2|Wr2]^T ---
  {
    int mtiles = (N + 31) >> 5;
    int waves = mtiles * 4;
    gemm_bf16_mfma<false><<<(waves + 3) / 4, 256, 0, stream>>>(
        hbf, wcat2, bl2, br2, (unsigned short*)xlr, nullptr, N, 4);
  }

  // --- layer 2 aggregation -> out ---
  {
    int blocks = 2048, nwaves = blocks * 4;
    gat_agg<2><<<blocks, 256, 0, stream>>>(xlr, meta, csr, att2,
                                           xres, bias2, ln_w, ln_b, d_out, N, nwaves);
  }
}